// Round 20
// baseline (209.208 us; speedup 1.0000x reference)
//
#include <hip/hip_runtime.h>

#define TT 256
#define BB 512
#define DD 128
#define HH 50
#define KK 5
#define AA 4
#define NROW 131072

typedef _Float16 half4 __attribute__((ext_vector_type(4)));
typedef float f32x4 __attribute__((ext_vector_type(4)));

// ---------------- K0: weight prep ----------------
__global__ void k0_prep(const float* __restrict__ W_in,
                        const float* __restrict__ W_ctx,
                        const float* __restrict__ W_key,
                        const float* __restrict__ W_q,
                        const float* __restrict__ b_key,
                        const float* __restrict__ b_q,
                        float* __restrict__ WHT,
                        float* __restrict__ WK2T, float* __restrict__ bias2) {
  int i = blockIdx.x * 256 + threadIdx.x;
  if (i < HH * 52) {
    int j = i / 52, h = i % 52;
    WHT[i] = (h < HH) ? W_ctx[h * (2 * HH) + HH + j] : 0.f;
  }
  if (i < HH * 64) {
    int j = i >> 6, l = i & 63;
    float v = 0.f;
    if (l < HH) v = W_ctx[l * (2 * HH) + j];
    else if (l < HH + KK) v = W_key[(l - HH) * HH + j];
    else if (l < HH + 2 * KK) v = W_q[(l - HH - KK) * HH + j];
    WK2T[i] = v;
  }
  if (i < 64) {
    float bv = 0.f;
    if (i >= HH && i < HH + KK) bv = b_key[i - HH];
    else if (i >= HH + KK && i < HH + 2 * KK) bv = b_q[i - HH - KK];
    bias2[i] = bv;
  }
}

// ---------------- K1 (MFMA, fused): g = relu(x@W_in^T+b_in)@Wh^T + b_ctx ---
// R19-verified. g stored f16 [chain][t][64], slots 50-63 zeroed.
__global__ __launch_bounds__(256, 2) void k1_mfma(
    const float* __restrict__ x, const float* __restrict__ W_in,
    const float* __restrict__ WHT, const float* __restrict__ b_in,
    const float* __restrict__ b_ctx, _Float16* __restrict__ gh) {
  const int lane = threadIdx.x & 63;
  const int wave = threadIdx.x >> 6;
  const int lrow = lane & 15, lgrp = lane >> 4;

#define WA1D(m, kk)                                                     \
  half4 wa1_##m##_##kk;                                                 \
  {                                                                     \
    const int hh = 16 * (m) + lrow;                                     \
    const int j0 = 16 * (kk) + 4 * lgrp;                                \
    const bool v = (hh < HH);                                           \
    const float* p = W_in + (size_t)(v ? hh : 0) * DD + j0;             \
    wa1_##m##_##kk[0] = (_Float16)(v ? p[0] : 0.f);                     \
    wa1_##m##_##kk[1] = (_Float16)(v ? p[1] : 0.f);                     \
    wa1_##m##_##kk[2] = (_Float16)(v ? p[2] : 0.f);                     \
    wa1_##m##_##kk[3] = (_Float16)(v ? p[3] : 0.f);                     \
  }
  WA1D(0, 0) WA1D(0, 1) WA1D(0, 2) WA1D(0, 3)
  WA1D(0, 4) WA1D(0, 5) WA1D(0, 6) WA1D(0, 7)
  WA1D(1, 0) WA1D(1, 1) WA1D(1, 2) WA1D(1, 3)
  WA1D(1, 4) WA1D(1, 5) WA1D(1, 6) WA1D(1, 7)
  WA1D(2, 0) WA1D(2, 1) WA1D(2, 2) WA1D(2, 3)
  WA1D(2, 4) WA1D(2, 5) WA1D(2, 6) WA1D(2, 7)
  WA1D(3, 0) WA1D(3, 1) WA1D(3, 2) WA1D(3, 3)
  WA1D(3, 4) WA1D(3, 5) WA1D(3, 6) WA1D(3, 7)

#define WA2D(m, kk)                                                     \
  half4 wa2_##m##_##kk;                                                 \
  {                                                                     \
    const int gg = 16 * (m) + lrow;                                     \
    const int h0 = 16 * (kk) + 4 * lgrp;                                \
    wa2_##m##_##kk[0] = (_Float16)((gg < HH && h0 + 0 < HH) ? WHT[(h0 + 0) * 52 + gg] : 0.f); \
    wa2_##m##_##kk[1] = (_Float16)((gg < HH && h0 + 1 < HH) ? WHT[(h0 + 1) * 52 + gg] : 0.f); \
    wa2_##m##_##kk[2] = (_Float16)((gg < HH && h0 + 2 < HH) ? WHT[(h0 + 2) * 52 + gg] : 0.f); \
    wa2_##m##_##kk[3] = (_Float16)((gg < HH && h0 + 3 < HH) ? WHT[(h0 + 3) * 52 + gg] : 0.f); \
  }
  WA2D(0, 0) WA2D(0, 1) WA2D(0, 2) WA2D(0, 3)
  WA2D(1, 0) WA2D(1, 1) WA2D(1, 2) WA2D(1, 3)
  WA2D(2, 0) WA2D(2, 1) WA2D(2, 2) WA2D(2, 3)
  WA2D(3, 0) WA2D(3, 1) WA2D(3, 2) WA2D(3, 3)

#define BDEF(m, r)                                                      \
  const float bin_##m##_##r =                                           \
      (16 * (m) + 4 * lgrp + (r) < HH) ? b_in[16 * (m) + 4 * lgrp + (r)] : 0.f; \
  const float bct_##m##_##r =                                           \
      (16 * (m) + 4 * lgrp + (r) < HH) ? b_ctx[16 * (m) + 4 * lgrp + (r)] : 0.f;
  BDEF(0, 0) BDEF(0, 1) BDEF(0, 2) BDEF(0, 3)
  BDEF(1, 0) BDEF(1, 1) BDEF(1, 2) BDEF(1, 3)
  BDEF(2, 0) BDEF(2, 1) BDEF(2, 2) BDEF(2, 3)
  BDEF(3, 0) BDEF(3, 1) BDEF(3, 2) BDEF(3, 3)

  const f32x4 zf = {0.f, 0.f, 0.f, 0.f};

#pragma unroll 1
  for (int it = 0; it < 4; ++it) {
    const int tile = (blockIdx.x * 4 + wave) * 4 + it;
    const int row = tile * 16 + lrow;
    const float* __restrict__ xr = x + (size_t)row * DD + 4 * lgrp;

#define XLD(kk)                                                         \
  half4 xb##kk;                                                         \
  {                                                                     \
    const float4 xv = *reinterpret_cast<const float4*>(xr + 16 * kk);   \
    xb##kk[0] = (_Float16)xv.x;                                         \
    xb##kk[1] = (_Float16)xv.y;                                         \
    xb##kk[2] = (_Float16)xv.z;                                         \
    xb##kk[3] = (_Float16)xv.w;                                         \
  }
    XLD(0) XLD(1) XLD(2) XLD(3) XLD(4) XLD(5) XLD(6) XLD(7)

    f32x4 d10 = zf, d11 = zf, d12 = zf, d13 = zf;
#define MM1(kk)                                                              \
  d10 = __builtin_amdgcn_mfma_f32_16x16x16f16(wa1_0_##kk, xb##kk, d10, 0, 0, 0); \
  d11 = __builtin_amdgcn_mfma_f32_16x16x16f16(wa1_1_##kk, xb##kk, d11, 0, 0, 0); \
  d12 = __builtin_amdgcn_mfma_f32_16x16x16f16(wa1_2_##kk, xb##kk, d12, 0, 0, 0); \
  d13 = __builtin_amdgcn_mfma_f32_16x16x16f16(wa1_3_##kk, xb##kk, d13, 0, 0, 0);
    MM1(0) MM1(1) MM1(2) MM1(3) MM1(4) MM1(5) MM1(6) MM1(7)

#define HBD(k)                                                    \
  half4 hb##k;                                                    \
  hb##k[0] = (_Float16)fmaxf(d1##k[0] + bin_##k##_0, 0.f);        \
  hb##k[1] = (_Float16)fmaxf(d1##k[1] + bin_##k##_1, 0.f);        \
  hb##k[2] = (_Float16)fmaxf(d1##k[2] + bin_##k##_2, 0.f);        \
  hb##k[3] = (_Float16)fmaxf(d1##k[3] + bin_##k##_3, 0.f);
    HBD(0) HBD(1) HBD(2) HBD(3)

    f32x4 d20 = zf, d21 = zf, d22 = zf, d23 = zf;
#define MM2(kk)                                                              \
  d20 = __builtin_amdgcn_mfma_f32_16x16x16f16(wa2_0_##kk, hb##kk, d20, 0, 0, 0); \
  d21 = __builtin_amdgcn_mfma_f32_16x16x16f16(wa2_1_##kk, hb##kk, d21, 0, 0, 0); \
  d22 = __builtin_amdgcn_mfma_f32_16x16x16f16(wa2_2_##kk, hb##kk, d22, 0, 0, 0); \
  d23 = __builtin_amdgcn_mfma_f32_16x16x16f16(wa2_3_##kk, hb##kk, d23, 0, 0, 0);
    MM2(0) MM2(1) MM2(2) MM2(3)

    _Float16* __restrict__ gr =
        gh + ((size_t)(row & (BB - 1)) * TT + (row >> 9)) * 64;
#define GST4(off, D, B0, B1, B2, B3)                          \
  {                                                           \
    half4 v;                                                  \
    v[0] = (_Float16)(D[0] + B0);                             \
    v[1] = (_Float16)(D[1] + B1);                             \
    v[2] = (_Float16)(D[2] + B2);                             \
    v[3] = (_Float16)(D[3] + B3);                             \
    *reinterpret_cast<half4*>(gr + (off) + 4 * lgrp) = v;     \
  }
    GST4(0, d20, bct_0_0, bct_0_1, bct_0_2, bct_0_3)
    GST4(16, d21, bct_1_0, bct_1_1, bct_1_2, bct_1_3)
    GST4(32, d22, bct_2_0, bct_2_1, bct_2_2, bct_2_3)
    {
      half4 v;
      v[0] = (_Float16)((lgrp == 0) ? d23[0] + bct_3_0 : 0.f);
      v[1] = (_Float16)((lgrp == 0) ? d23[1] + bct_3_1 : 0.f);
      v[2] = (_Float16)0.f;
      v[3] = (_Float16)0.f;
      *reinterpret_cast<half4*>(gr + 48 + 4 * lgrp) = v;
    }
  }
}

// ---------------- K2: MFMA recurrence (32 blocks x 1 wave) -----------------
// R16-verified compute core (16 MFMA/step, no LDS, all-to-all inside matrix
// unit). NEW egress: ctx stored [t][chain][64] — one step's output is a
// CONTIGUOUS 4KB block = 4 float4 stores, full 64B lines, no RMW (R13's
// 16-far-lines-per-instr partial-write scatter was the stall). kq stored
// [t][chain][12].
__global__ __launch_bounds__(64, 1) void k2_mfma(
    const _Float16* __restrict__ gh, const float* __restrict__ WK2T,
    const float* __restrict__ bias2, const float* __restrict__ fc,
    float* __restrict__ ctxT, float* __restrict__ kqT) {
  const int lane = threadIdx.x;
  const int lrow = lane & 15, lgrp = lane >> 4;
  const int chain0 = blockIdx.x * 16;
  const int chain = chain0 + lrow;

#define DECLWF(m, kk)                                                       \
  half4 wf_##m##_##kk;                                                      \
  {                                                                         \
    const int j0 = (kk) * 16 + 4 * lgrp;                                    \
    wf_##m##_##kk[0] = (_Float16)((j0 + 0 < HH) ? WK2T[(j0 + 0) * 64 + (m) * 16 + lrow] : 0.f); \
    wf_##m##_##kk[1] = (_Float16)((j0 + 1 < HH) ? WK2T[(j0 + 1) * 64 + (m) * 16 + lrow] : 0.f); \
    wf_##m##_##kk[2] = (_Float16)((j0 + 2 < HH) ? WK2T[(j0 + 2) * 64 + (m) * 16 + lrow] : 0.f); \
    wf_##m##_##kk[3] = (_Float16)((j0 + 3 < HH) ? WK2T[(j0 + 3) * 64 + (m) * 16 + lrow] : 0.f); \
  }
  DECLWF(0, 0) DECLWF(0, 1) DECLWF(0, 2) DECLWF(0, 3)
  DECLWF(1, 0) DECLWF(1, 1) DECLWF(1, 2) DECLWF(1, 3)
  DECLWF(2, 0) DECLWF(2, 1) DECLWF(2, 2) DECLWF(2, 3)
  DECLWF(3, 0) DECLWF(3, 1) DECLWF(3, 2) DECLWF(3, 3)

  const float bias_0 = bias2[48 + 4 * lgrp + 0];
  const float bias_1 = bias2[48 + 4 * lgrp + 1];
  const float bias_2 = bias2[48 + 4 * lgrp + 2];
  const float bias_3 = bias2[48 + 4 * lgrp + 3];
#define KQR(r)                                            \
  const int row_##r = 48 + 4 * lgrp + r;                  \
  const bool kv_##r = (row_##r >= 50 && row_##r < 60);
  KQR(0) KQR(1) KQR(2) KQR(3)

#define DECLBF(kk)                                                  \
  half4 bf_##kk;                                                    \
  {                                                                 \
    const int j0 = (kk) * 16 + 4 * lgrp;                            \
    bf_##kk[0] = (_Float16)((j0 + 0 < HH) ? fc[j0 + 0] : 0.f);      \
    bf_##kk[1] = (_Float16)((j0 + 1 < HH) ? fc[j0 + 1] : 0.f);      \
    bf_##kk[2] = (_Float16)((j0 + 2 < HH) ? fc[j0 + 2] : 0.f);      \
    bf_##kk[3] = (_Float16)((j0 + 3 < HH) ? fc[j0 + 3] : 0.f);      \
  }
  DECLBF(0) DECLBF(1) DECLBF(2) DECLBF(3)

  // ctx[t=0][chain][h] = c0
  for (int i = lane; i < 16 * 64; i += 64) {
    const int c = i >> 6, h = i & 63;
    ctxT[((size_t)0 * BB + chain0 + c) * 64 + h] = (h < HH) ? fc[h] : 0.f;
  }

  const _Float16* __restrict__ ghp = gh + (size_t)chain * TT * 64 + 4 * lgrp;

  half4 gA0 = *(const half4*)(ghp + 0 * 64 + 0);
  half4 gA1 = *(const half4*)(ghp + 0 * 64 + 16);
  half4 gA2 = *(const half4*)(ghp + 0 * 64 + 32);
  half4 gA3 = *(const half4*)(ghp + 0 * 64 + 48);
  half4 gB0 = *(const half4*)(ghp + 1 * 64 + 0);
  half4 gB1 = *(const half4*)(ghp + 1 * 64 + 16);
  half4 gB2 = *(const half4*)(ghp + 1 * 64 + 32);
  half4 gB3 = *(const half4*)(ghp + 1 * 64 + 48);

  const f32x4 zf = {0.f, 0.f, 0.f, 0.f};

#define MM(D, A, B) D = __builtin_amdgcn_mfma_f32_16x16x16f16(A, B, D, 0, 0, 0);
#define MSTEP(T, G0, G1, G2, G3, TPF)                                      \
  {                                                                        \
    f32x4 d0 = zf, d1 = zf, d2 = zf, d3 = zf;                              \
    MM(d0, wf_0_0, bf_0) MM(d1, wf_1_0, bf_0)                              \
    MM(d2, wf_2_0, bf_0) MM(d3, wf_3_0, bf_0)                              \
    MM(d0, wf_0_1, bf_1) MM(d1, wf_1_1, bf_1)                              \
    MM(d2, wf_2_1, bf_1) MM(d3, wf_3_1, bf_1)                              \
    MM(d0, wf_0_2, bf_2) MM(d1, wf_1_2, bf_2)                              \
    MM(d2, wf_2_2, bf_2) MM(d3, wf_3_2, bf_2)                              \
    MM(d0, wf_0_3, bf_3) MM(d1, wf_1_3, bf_3)                              \
    MM(d2, wf_2_3, bf_3) MM(d3, wf_3_3, bf_3)                              \
    {                                                                      \
      float* kqo = kqT + ((size_t)(T) * BB + chain) * 12;                  \
      if (kv_0) kqo[row_0 - 50] = d3[0] + bias_0;                          \
      if (kv_1) kqo[row_1 - 50] = d3[1] + bias_1;                          \
      if (kv_2) kqo[row_2 - 50] = d3[2] + bias_2;                          \
      if (kv_3) kqo[row_3 - 50] = d3[3] + bias_3;                          \
    }                                                                      \
    const float cn_0_0 = fmaxf(d0[0] + (float)G0[0], 0.f);                 \
    const float cn_0_1 = fmaxf(d0[1] + (float)G0[1], 0.f);                 \
    const float cn_0_2 = fmaxf(d0[2] + (float)G0[2], 0.f);                 \
    const float cn_0_3 = fmaxf(d0[3] + (float)G0[3], 0.f);                 \
    const float cn_1_0 = fmaxf(d1[0] + (float)G1[0], 0.f);                 \
    const float cn_1_1 = fmaxf(d1[1] + (float)G1[1], 0.f);                 \
    const float cn_1_2 = fmaxf(d1[2] + (float)G1[2], 0.f);                 \
    const float cn_1_3 = fmaxf(d1[3] + (float)G1[3], 0.f);                 \
    const float cn_2_0 = fmaxf(d2[0] + (float)G2[0], 0.f);                 \
    const float cn_2_1 = fmaxf(d2[1] + (float)G2[1], 0.f);                 \
    const float cn_2_2 = fmaxf(d2[2] + (float)G2[2], 0.f);                 \
    const float cn_2_3 = fmaxf(d2[3] + (float)G2[3], 0.f);                 \
    const float cn_3_0 = fmaxf(d3[0] + (float)G3[0], 0.f);                 \
    const float cn_3_1 = fmaxf(d3[1] + (float)G3[1], 0.f);                 \
    const float cn_3_2 = fmaxf(d3[2] + (float)G3[2], 0.f);                 \
    const float cn_3_3 = fmaxf(d3[3] + (float)G3[3], 0.f);                 \
    G0 = *(const half4*)(ghp + (size_t)((TPF) < TT ? (TPF) : TT - 1) * 64 + 0);  \
    G1 = *(const half4*)(ghp + (size_t)((TPF) < TT ? (TPF) : TT - 1) * 64 + 16); \
    G2 = *(const half4*)(ghp + (size_t)((TPF) < TT ? (TPF) : TT - 1) * 64 + 32); \
    G3 = *(const half4*)(ghp + (size_t)((TPF) < TT ? (TPF) : TT - 1) * 64 + 48); \
    float* cto = ctxT + ((size_t)((T) + 1) * BB + chain) * 64 + 4 * lgrp;  \
    *reinterpret_cast<float4*>(cto + 0) =                                  \
        make_float4(cn_0_0, cn_0_1, cn_0_2, cn_0_3);                       \
    *reinterpret_cast<float4*>(cto + 16) =                                 \
        make_float4(cn_1_0, cn_1_1, cn_1_2, cn_1_3);                       \
    *reinterpret_cast<float4*>(cto + 32) =                                 \
        make_float4(cn_2_0, cn_2_1, cn_2_2, cn_2_3);                       \
    *reinterpret_cast<float4*>(cto + 48) =                                 \
        make_float4(cn_3_0, cn_3_1, cn_3_2, cn_3_3);                       \
    bf_0[0] = (_Float16)cn_0_0; bf_0[1] = (_Float16)cn_0_1;                \
    bf_0[2] = (_Float16)cn_0_2; bf_0[3] = (_Float16)cn_0_3;                \
    bf_1[0] = (_Float16)cn_1_0; bf_1[1] = (_Float16)cn_1_1;                \
    bf_1[2] = (_Float16)cn_1_2; bf_1[3] = (_Float16)cn_1_3;                \
    bf_2[0] = (_Float16)cn_2_0; bf_2[1] = (_Float16)cn_2_1;                \
    bf_2[2] = (_Float16)cn_2_2; bf_2[3] = (_Float16)cn_2_3;                \
    bf_3[0] = (_Float16)cn_3_0; bf_3[1] = (_Float16)cn_3_1;                \
    bf_3[2] = (_Float16)cn_3_2; bf_3[3] = (_Float16)cn_3_3;                \
  }

#pragma unroll 1
  for (int t = 0; t < TT; t += 2) {
    MSTEP(t, gA0, gA1, gA2, gA3, t + 2)
    MSTEP(t + 1, gB0, gB1, gB2, gB3, t + 3)
  }

  {  // tail: key/q of c_TT at index TT
    f32x4 d3 = zf;
    MM(d3, wf_3_0, bf_0) MM(d3, wf_3_1, bf_1)
    MM(d3, wf_3_2, bf_2) MM(d3, wf_3_3, bf_3)
    float* kqo = kqT + ((size_t)TT * BB + chain) * 12;
    if (kv_0) kqo[row_0 - 50] = d3[0] + bias_0;
    if (kv_1) kqo[row_1 - 50] = d3[1] + bias_1;
    if (kv_2) kqo[row_2 - 50] = d3[2] + bias_2;
    if (kv_3) kqo[row_3 - 50] = d3[3] + bias_3;
  }
}

// ---------------- K3: MFMA flash attention (transposed-layout inputs) ------
// ctx rows: ctxT[(s*BB + b)*64 + h]; keys kqT[(s*BB + b)*12 + k] (k 0-4);
// q for output t: kqT[((t+1)*BB + b)*12 + 5 + k]. k_l rows 5-15 hard-zeroed.
__global__ __launch_bounds__(256, 4) void k3_attn(
    const float* __restrict__ ctxT, const float* __restrict__ kqT,
    const float* __restrict__ W_act, const float* __restrict__ b_act,
    float* __restrict__ out) {
  __shared__ __align__(16) float ct[64 * 66];
  __shared__ __align__(16) float k_l[16 * 68];
  __shared__ __align__(16) float o_l[64 * 66];
  __shared__ float su_l[64];

  const int tid = threadIdx.x;
  const int bid = blockIdx.x;
  const int chunk = 3 - (bid >> 9);  // heavy-first
  const int b = bid & 511;
  const int tbase = chunk * 64;
  const int nst = min(tbase + 66, 257);
  const int ntiles = (nst + 63) >> 6;
  const int wave = tid >> 6;
  const int lane = tid & 63;
  const int lrow = lane & 15;
  const int lgrp = lane >> 4;
  const int tw = tbase + wave * 16;

  for (int i = tid; i < 11 * 68; i += 256) k_l[5 * 68 + i] = 0.f;

  half4 qf;
#pragma unroll
  for (int i = 0; i < 4; ++i) {
    const int k = 4 * lgrp + i;
    qf[i] = (_Float16)(
        (k < KK) ? kqT[((size_t)(tw + lrow + 1) * BB + b) * 12 + 5 + k] : 0.f);
  }

  const f32x4 zf = {0.f, 0.f, 0.f, 0.f};
  f32x4 acc0 = zf, acc1 = zf, acc2 = zf, acc3 = zf;
  float su = 0.f;

#pragma unroll 1
  for (int tile = 0; tile < ntiles; ++tile) {
    __syncthreads();
    {
      const int r = tid >> 2;
      const int c0 = (tid & 3) * 16;
      const int srow = tile * 64 + r;
      const float* src = ctxT + ((size_t)srow * BB + b) * 64;
      const bool sv = (srow < nst);
#pragma unroll
      for (int u = 0; u < 8; ++u) {
        const int c = c0 + u * 2;
        float2 v = make_float2(0.f, 0.f);
        if (sv && c < HH) v = *reinterpret_cast<const float2*>(src + c);
        *reinterpret_cast<float2*>(&ct[r * 66 + c]) = v;
      }
    }
    {
      for (int i = tid; i < KK * 64; i += 256) {
        const int k = i >> 6, sl = i & 63;
        const int s = tile * 64 + sl;
        k_l[k * 68 + sl] =
            (s <= TT) ? kqT[((size_t)s * BB + b) * 12 + k] : 0.f;
      }
    }
    __syncthreads();

    if (tile * 64 <= tw + 16) {
#pragma unroll 1
      for (int su16 = 0; su16 < 4; ++su16) {
        const int sb = tile * 64 + su16 * 16;
        if (sb > tw + 16) break;

        half4 kf;
#pragma unroll
        for (int i = 0; i < 4; ++i)
          kf[i] = (_Float16)k_l[(4 * lgrp + i) * 68 + su16 * 16 + lrow];

        const f32x4 sc =
            __builtin_amdgcn_mfma_f32_16x16x16f16(kf, qf, zf, 0, 0, 0);

        half4 pa;
#pragma unroll
        for (int r = 0; r < 4; ++r) {
          const int s = sb + 4 * lgrp + r;
          const float p = (s <= tw + lrow + 1) ? __expf(sc[r]) : 0.f;
          su += p;
          pa[r] = (_Float16)p;
        }

        const int vbase = su16 * 16 + 4 * lgrp;
#define PVHT(HT, ACC)                                                     \
  {                                                                       \
    half4 vf;                                                             \
    vf[0] = (_Float16)ct[(vbase + 0) * 66 + lrow + 16 * HT];              \
    vf[1] = (_Float16)ct[(vbase + 1) * 66 + lrow + 16 * HT];              \
    vf[2] = (_Float16)ct[(vbase + 2) * 66 + lrow + 16 * HT];              \
    vf[3] = (_Float16)ct[(vbase + 3) * 66 + lrow + 16 * HT];              \
    ACC = __builtin_amdgcn_mfma_f32_16x16x16f16(pa, vf, ACC, 0, 0, 0);    \
  }
        PVHT(0, acc0) PVHT(1, acc1) PVHT(2, acc2) PVHT(3, acc3)
      }
    }
  }

  su += __shfl_xor(su, 16, 64);
  su += __shfl_xor(su, 32, 64);
  if (lane < 16) su_l[wave * 16 + lane] = su;

#pragma unroll
  for (int r = 0; r < 4; ++r) {
    const int trow = wave * 16 + 4 * lgrp + r;
    o_l[trow * 66 + lrow + 0] = acc0[r];
    o_l[trow * 66 + lrow + 16] = acc1[r];
    o_l[trow * 66 + lrow + 32] = acc2[r];
    o_l[trow * 66 + lrow + 48] = acc3[r];
  }
  __syncthreads();

  {
    const int tl = tid >> 2;
    const int a = tid & 3;
    const float inv = 1.f / su_l[tl];
    const float* orow = &o_l[tl * 66];
    const float* wrow = W_act + a * HH;
    float s0 = 0.f, s1 = 0.f;
#pragma unroll
    for (int h = 0; h < HH; h += 2) {
      s0 = fmaf(orow[h], wrow[h], s0);
      s1 = fmaf(orow[h + 1], wrow[h + 1], s1);
    }
    out[((size_t)(tbase + tl) * BB + b) * AA + a] =
        fmaf(s0 + s1, inv, b_act[a]);
  }
}

extern "C" void kernel_launch(void* const* d_in, const int* in_sizes, int n_in,
                              void* d_out, int out_size, void* d_ws,
                              size_t ws_size, hipStream_t stream) {
  const float* x = (const float*)d_in[0];
  const float* W_in = (const float*)d_in[1];
  const float* b_in = (const float*)d_in[2];
  const float* W_ctx = (const float*)d_in[3];
  const float* b_ctx = (const float*)d_in[4];
  const float* W_key = (const float*)d_in[5];
  const float* b_key = (const float*)d_in[6];
  const float* W_q = (const float*)d_in[7];
  const float* b_q = (const float*)d_in[8];
  const float* fc = (const float*)d_in[9];
  const float* W_act = (const float*)d_in[10];
  const float* b_act = (const float*)d_in[11];
  float* out = (float*)d_out;
  float* ws = (float*)d_ws;

  float* WHT = ws;                                  // 50*52
  float* WK2T = ws + 4096;                          // 50*64
  float* bias2 = ws + 8128;                         // 64
  _Float16* gh = (_Float16*)(ws + 8192);            // 131072*64 f16 (16.8MB)
  float* ctxT = ws + 8192 + 4194304;                // 257*512*64 (33.7MB)
  float* kqT = ctxT + (size_t)257 * BB * 64;        // 257*512*12 (6.3MB)
  // total ~57 MB

  hipLaunchKernelGGL(k0_prep, dim3(26), dim3(256), 0, stream, W_in, W_ctx,
                     W_key, W_q, b_key, b_q, WHT, WK2T, bias2);
  hipLaunchKernelGGL(k1_mfma, dim3(512), dim3(256), 0, stream, x, W_in, WHT,
                     b_in, b_ctx, gh);
  hipLaunchKernelGGL(k2_mfma, dim3(32), dim3(64), 0, stream, gh, WK2T, bias2,
                     fc, ctxT, kqT);
  hipLaunchKernelGGL(k3_attn, dim3(2048), dim3(256), 0, stream, ctxT, kqT,
                     W_act, b_act, out);
}